// Round 2
// baseline (8863.838 us; speedup 1.0000x reference)
//
#include <hip/hip_runtime.h>

// GRUNet: 2-layer GRU (B=128, T=512, I=64, H=256) + ReLU + FC(256->2).
// Round 2: persistent cooperative kernel.
//   - 256 WGs (128 per layer), 256 threads, 1 WG/CU.
//   - Weights staged to LDS ONCE; 513-step loop inside the kernel.
//   - Cross-step sync: generation-counting grid barrier with agent-scope
//     atomics (release flushes XCD L2, acquire invalidates -> h coherent).
//   - Layer pipeline: step s computes layer0 t=s and layer1 t=s-1.
//   - FC epilogue in WG0 after the final barrier.

namespace {
constexpr int kB = 128;
constexpr int kT = 512;
constexpr int kI = 64;
constexpr int kH = 256;

constexpr int BT = 32;              // batch rows per WG
constexpr int JT = 8;               // hidden units per WG
constexpr int PH = 260;             // LDS stride for 256-wide rows (jj-stride 1040B -> bank offset 4, conflict-free)
constexpr int PX = 68;              // LDS stride for 64-wide rows
constexpr int NB = kB / BT;         // 4
constexpr int NJ = kH / JT;         // 32
constexpr int WPL = NB * NJ;        // 128 WGs per layer
constexpr int NWG = 2 * WPL;        // 256 total

constexpr int kLdsFloats = 3 * JT * (PH + PH);  // layer1 worst case: 12480 floats
}

__device__ __forceinline__ float sigf(float v) { return 1.0f / (1.0f + expf(-v)); }

// Grid barrier, generation 'gen' (1-based). Central counter + release word.
__device__ __forceinline__ void grid_bar(unsigned* cnt, unsigned* rel, unsigned gen) {
  __syncthreads();   // all WG lanes done (incl. vmcnt drain of h stores)
  if (threadIdx.x == 0) {
    unsigned prev = __hip_atomic_fetch_add(cnt, 1u, __ATOMIC_ACQ_REL, __HIP_MEMORY_SCOPE_AGENT);
    if (prev == gen * (unsigned)NWG - 1u) {
      __hip_atomic_store(rel, gen, __ATOMIC_RELEASE, __HIP_MEMORY_SCOPE_AGENT);
    } else {
      while (__hip_atomic_load(rel, __ATOMIC_RELAXED, __HIP_MEMORY_SCOPE_AGENT) < gen) {
        __builtin_amdgcn_s_sleep(1);
      }
      (void)__hip_atomic_load(rel, __ATOMIC_ACQUIRE, __HIP_MEMORY_SCOPE_AGENT);
    }
  }
  __syncthreads();
}

// 3-gate dot: a[0..IDIM) (global) against LDS rows {g*JT+jj} for g=0,1,2.
template <int IDIM, int IPAD>
__device__ __forceinline__ void dot3(const float* __restrict__ a,
                                     const float* w, int jj,
                                     float& r0, float& r1, float& r2) {
  float s0 = 0.f, s1 = 0.f, s2 = 0.f;
  #pragma unroll 8
  for (int k = 0; k < IDIM; k += 4) {
    const float4 av = *(const float4*)(a + k);
    const float4 w0 = *(const float4*)(w + (0 * JT + jj) * IPAD + k);
    const float4 w1 = *(const float4*)(w + (1 * JT + jj) * IPAD + k);
    const float4 w2 = *(const float4*)(w + (2 * JT + jj) * IPAD + k);
    s0 += av.x * w0.x + av.y * w0.y + av.z * w0.z + av.w * w0.w;
    s1 += av.x * w1.x + av.y * w1.y + av.z * w1.z + av.w * w1.w;
    s2 += av.x * w2.x + av.y * w2.y + av.z * w2.z + av.w * w2.w;
  }
  r0 = s0; r1 = s1; r2 = s2;
}

__global__ __launch_bounds__(256, 1) void gru_persistent(
    const float* __restrict__ x,
    const float* __restrict__ wih0, const float* __restrict__ whh0,
    const float* __restrict__ bih0, const float* __restrict__ bhh0,
    const float* __restrict__ wih1, const float* __restrict__ whh1,
    const float* __restrict__ bih1, const float* __restrict__ bhh1,
    const float* __restrict__ fcw, const float* __restrict__ fcb,
    float* __restrict__ h0buf, float* __restrict__ h1buf,
    unsigned* cnt, unsigned* rel, float* out)
{
  const int bid   = blockIdx.x;
  const int layer = bid >> 7;
  const int wid   = bid & (WPL - 1);
  const int tid   = threadIdx.x;

  const int b0 = (wid & (NB - 1)) * BT;
  const int j0 = (wid >> 2) * JT;

  const float* win = (layer == 0) ? wih0 : wih1;
  const float* whh = (layer == 0) ? whh0 : whh1;
  const float* bih = (layer == 0) ? bih0 : bih1;
  const float* bhh = (layer == 0) ? bhh0 : bhh1;
  const int idim = (layer == 0) ? kI : kH;
  const int ipad = (layer == 0) ? PX : PH;

  // ---- stage this WG's 24 weight rows into LDS (once) ----
  __shared__ float lds[kLdsFloats];
  float* w_in = lds;
  float* w_h  = lds + 3 * JT * ipad;
  {
    const int pr = idim / 4;
    for (int i = tid; i < 3 * JT * pr; i += 256) {
      const int r = i / pr, c = (i - r * pr) * 4;
      const int g = r / JT, jr = r - g * JT;
      *(float4*)(w_in + r * ipad + c) =
          *(const float4*)(win + (size_t)(g * kH + j0 + jr) * idim + c);
    }
    for (int i = tid; i < 3 * JT * 64; i += 256) {
      const int r = i / 64, c = (i - r * 64) * 4;
      const int g = r / JT, jr = r - g * JT;
      *(float4*)(w_h + r * PH + c) =
          *(const float4*)(whh + (size_t)(g * kH + j0 + jr) * kH + c);
    }
  }

  // ---- per-thread invariants ----
  const int jj = tid & (JT - 1);
  const int b  = tid >> 3;
  const int j  = j0 + jj;
  const int br = b0 + b;                 // global batch row

  const float br_r = bih[j]          + bhh[j];
  const float br_z = bih[kH + j]     + bhh[kH + j];
  const float bn_i = bih[2 * kH + j];
  const float bn_h = bhh[2 * kH + j];

  __syncthreads();

  // ---- 513 pipelined steps ----
  for (int s = 0; s <= kT; ++s) {
    const bool active = (layer == 0) ? (s < kT) : (s >= 1);
    if (active) {
      const int t = (layer == 0) ? s : (s - 1);
      const float* arow = (layer == 0)
          ? (x + (size_t)br * kT * kI + (size_t)t * kI)
          : (h0buf + (size_t)(t & 1) * kB * kH + (size_t)br * kH);
      const float* hrow = ((layer == 0)
          ? (h0buf + (size_t)((s + 1) & 1) * kB * kH)
          : (h1buf + (size_t)(s & 1) * kB * kH)) + (size_t)br * kH;
      float* hout = (layer == 0)
          ? (h0buf + (size_t)(s & 1) * kB * kH)
          : (h1buf + (size_t)((s - 1) & 1) * kB * kH);

      float xr, xz, xn, hr, hz, hn;
      if (layer == 0) dot3<kI, PX>(arow, w_in, jj, xr, xz, xn);
      else            dot3<kH, PH>(arow, w_in, jj, xr, xz, xn);
      dot3<kH, PH>(hrow, w_h, jj, hr, hz, hn);

      const float rr = sigf(xr + hr + br_r);
      const float zz = sigf(xz + hz + br_z);
      const float nn = tanhf(xn + bn_i + rr * (hn + bn_h));
      const float hp = hrow[j];
      hout[(size_t)br * kH + j] = (1.f - zz) * nn + zz * hp;
    }
    grid_bar(cnt, rel, (unsigned)(s + 1));
  }

  // ---- FC epilogue: out[b][o] = fc_b[o] + sum relu(h1(T-1)) * fc_w[o][:] ----
  if (bid == 0) {
    const int o = tid & 1, bb = tid >> 1;
    const float* hf = h1buf + (size_t)1 * kB * kH + (size_t)bb * kH;  // parity (T-1)&1 == 1
    const float* wr = fcw + (size_t)o * kH;
    float acc = fcb[o];
    #pragma unroll 8
    for (int k = 0; k < kH; k += 4) {
      const float4 hv = *(const float4*)(hf + k);
      const float4 wv = *(const float4*)(wr + k);
      acc += fmaxf(hv.x, 0.f) * wv.x + fmaxf(hv.y, 0.f) * wv.y +
             fmaxf(hv.z, 0.f) * wv.z + fmaxf(hv.w, 0.f) * wv.w;
    }
    out[bb * 2 + o] = acc;
  }
}

extern "C" void kernel_launch(void* const* d_in, const int* in_sizes, int n_in,
                              void* d_out, int out_size, void* d_ws, size_t ws_size,
                              hipStream_t stream) {
  const float* x    = (const float*)d_in[0];
  const float* wih0 = (const float*)d_in[1];
  const float* whh0 = (const float*)d_in[2];
  const float* bih0 = (const float*)d_in[3];
  const float* bhh0 = (const float*)d_in[4];
  const float* wih1 = (const float*)d_in[5];
  const float* whh1 = (const float*)d_in[6];
  const float* bih1 = (const float*)d_in[7];
  const float* bhh1 = (const float*)d_in[8];
  const float* fcw  = (const float*)d_in[9];
  const float* fcb  = (const float*)d_in[10];

  float* h0buf = (float*)d_ws;                   // [2][B][H]
  float* h1buf = h0buf + 2 * kB * kH;            // [2][B][H]
  unsigned* cnt = (unsigned*)(h1buf + 2 * kB * kH);
  unsigned* rel = cnt + 64;                      // separate cacheline
  float* out = (float*)d_out;

  // zero h(-1) double-buffers + barrier state every call (deterministic)
  hipMemsetAsync(d_ws, 0, (size_t)(4 * kB * kH) * sizeof(float) + 512, stream);

  void* args[] = { &x, &wih0, &whh0, &bih0, &bhh0, &wih1, &whh1, &bih1, &bhh1,
                   &fcw, &fcb, &h0buf, &h1buf, &cnt, &rel, &out };
  hipLaunchCooperativeKernel((void*)gru_persistent, dim3(NWG), dim3(256),
                             args, 0, stream);
}